// Round 3
// 419.679 us; speedup vs baseline: 1.0067x; 1.0067x over previous
//
#include <hip/hip_runtime.h>
#include <math.h>

#define B_ 32
#define L_ 8192
#define D_ 256
#define M_ 4097   // L/2 + 1

// ---------------------------------------------------------------------------
// K1: s[b,l] = sigmoid(dot(x[b,l,:], W) + bias).  One wave (64 lanes) per row,
// each lane loads a float4 of x and W (64*4 = 256 = D), shuffle-xor reduce.
// Memory-bound at ~268 MB read; unchanged (passed in round 0).
// ---------------------------------------------------------------------------
__global__ __launch_bounds__(256) void k_sigmoid_dot(
    const float* __restrict__ x, const float* __restrict__ W,
    const float* __restrict__ bias, float* __restrict__ s)
{
    int row  = (blockIdx.x << 2) + (threadIdx.x >> 6);   // 4 waves/block
    int lane = threadIdx.x & 63;
    const float4 xv = ((const float4*)(x + (size_t)row * D_))[lane];
    const float4 wv = ((const float4*)W)[lane];
    float p = xv.x * wv.x + xv.y * wv.y + xv.z * wv.z + xv.w * wv.w;
#pragma unroll
    for (int off = 32; off > 0; off >>= 1)
        p += __shfl_xor(p, off, 64);
    if (lane == 0) {
        float z = p + bias[0];
        s[row] = 1.0f / (1.0f + expf(-z));
    }
}

// ---------------------------------------------------------------------------
// K2: per batch: strict-local-min mask (zero-padded neighbors, frame 0 forced
// true), wave-shuffle scan for prefix ranks, and emit a packed 16 B record
// per valley: (w0 = s0*inv, w1 = s1*inv, p) so K3 does ONE dwordx4 load
// instead of the starts -> s[p] -> s[p+1] dependent chain.
// One block (256 threads) per batch; each thread owns 32 contiguous frames,
// bulk-loaded as 8x float4 (independent loads, latency hidden).
// ---------------------------------------------------------------------------
__global__ __launch_bounds__(256) void k_scan(
    const float* __restrict__ s, float4* __restrict__ rec,
    int* __restrict__ counts, float* __restrict__ out_counts)
{
    int b = blockIdx.x;
    const float* sb = s + (size_t)b * L_;
    int t    = threadIdx.x;
    int wid  = t >> 6;
    int lane = t & 63;
    int base = t * 32;

    // vals[j] = s[base - 1 + j], j in [0, 33]; zero-padded at both ends.
    float vals[34];
    vals[0]  = (base == 0) ? 0.0f : sb[base - 1];
    const float4* sb4 = (const float4*)(sb + base);
#pragma unroll
    for (int j = 0; j < 8; j++) {
        float4 q = sb4[j];
        vals[1 + 4 * j] = q.x; vals[2 + 4 * j] = q.y;
        vals[3 + 4 * j] = q.z; vals[4 + 4 * j] = q.w;
    }
    vals[33] = (base + 32 >= L_) ? 0.0f : sb[base + 32];

    unsigned bits = 0;
    int cnt = 0;
#pragma unroll
    for (int i = 0; i < 32; i++) {
        bool m = (base + i == 0)
                 ? true
                 : ((vals[i + 1] < vals[i]) && (vals[i + 1] < vals[i + 2]));
        if (m) { bits |= (1u << i); cnt++; }
    }

    // Wave-level inclusive scan (no barriers), then cross-wave offsets.
    int v = cnt;
#pragma unroll
    for (int off = 1; off < 64; off <<= 1) {
        int u = __shfl_up(v, off, 64);
        if (lane >= off) v += u;
    }
    __shared__ int wsum[4];
    if (lane == 63) wsum[wid] = v;
    __syncthreads();
    int wo = 0;
#pragma unroll
    for (int w = 0; w < 4; w++)
        if (w < wid) wo += wsum[w];
    int excl  = v + wo - cnt;
    int total = wsum[0] + wsum[1] + wsum[2] + wsum[3];

    int k = excl;
#pragma unroll
    for (int i = 0; i < 32; i++) {
        if (bits & (1u << i)) {
            if (k < M_) {                    // defensive: cannot write OOB
                int   p  = base + i;
                float s0 = vals[i + 1];
                float s1 = vals[i + 2];      // == 0 automatically at p == L-1
                float inv = 1.0f / fmaxf(s0 + s1, 1e-6f);
                float4 r;
                r.x = s0 * inv;
                r.y = s1 * inv;
                r.z = __int_as_float(p);
                r.w = 0.0f;
                rec[(size_t)b * M_ + k] = r;
            }
            k++;
        }
    }
    if (t == 0) {
        counts[b]     = total;
        out_counts[b] = (float)total;   // harness reads flat out buffer as f32
    }
}

// ---------------------------------------------------------------------------
// K3: 256-thread blocks, 8 output rows per block (2 per wave, independent ->
// ILP hides the rec-load + x-row-load chain).  k >= count -> zeros (d_out is
// poisoned before every timed launch).  Second x row is loaded
// unconditionally with a clamped pointer (weight is 0 at the edge).
// ---------------------------------------------------------------------------
__global__ __launch_bounds__(256) void k_write(
    const float* __restrict__ x, const float4* __restrict__ rec,
    const int* __restrict__ counts, float* __restrict__ out)
{
    int b    = blockIdx.y;
    int wid  = threadIdx.x >> 6;
    int lane = threadIdx.x & 63;
    int cnt  = counts[b];
    if (cnt > M_) cnt = M_;              // defensive clamp
    int kb   = blockIdx.x * 8 + wid;
#pragma unroll
    for (int rr = 0; rr < 2; rr++) {
        int k = kb + (rr << 2);
        if (k >= M_) continue;
        float4* orow = (float4*)(out + ((size_t)b * M_ + k) * D_);
        if (k >= cnt) {
            orow[lane] = make_float4(0.f, 0.f, 0.f, 0.f);
            continue;
        }
        float4 r4 = rec[(size_t)b * M_ + k];
        int p = __float_as_int(r4.z);
        if (p < 0) p = 0;
        if (p > L_ - 1) p = L_ - 1;      // defensive clamp
        const float4* xp = (const float4*)(x + ((size_t)b * L_ + p) * D_);
        float4 a = xp[lane];
        const float4* xq = xp + ((p + 1 < L_) ? (D_ / 4) : 0);
        float4 c = xq[lane];
        float4 r;
        r.x = r4.x * a.x + r4.y * c.x;
        r.y = r4.x * a.y + r4.y * c.y;
        r.z = r4.x * a.z + r4.y * c.z;
        r.w = r4.x * a.w + r4.y * c.w;
        orow[lane] = r;
    }
}

extern "C" void kernel_launch(void* const* d_in, const int* in_sizes, int n_in,
                              void* d_out, int out_size, void* d_ws, size_t ws_size,
                              hipStream_t stream) {
    const float* x    = (const float*)d_in[0];
    // d_in[1] = olens: unused by the reference
    const float* W    = (const float*)d_in[2];
    const float* bias = (const float*)d_in[3];

    float* out        = (float*)d_out;
    float* out_counts = out + (size_t)B_ * M_ * D_;   // counts tail, as f32

    float*  s      = (float*)d_ws;                                    // B*L f32   (1 MB)
    float4* rec    = (float4*)((char*)d_ws + (size_t)B_ * L_ * 4);    // B*M*16 B  (2 MB)
    int*    counts = (int*)((char*)rec + (size_t)B_ * M_ * 16);       // B i32

    k_sigmoid_dot<<<(B_ * L_) / 4, 256, 0, stream>>>(x, W, bias, s);
    k_scan<<<B_, 256, 0, stream>>>(s, rec, counts, out_counts);
    k_write<<<dim3((M_ + 7) / 8, B_), 256, 0, stream>>>(x, rec, counts, out);
}

// Round 5
// 415.503 us; speedup vs baseline: 1.0168x; 1.0101x over previous
//
#include <hip/hip_runtime.h>
#include <math.h>

#define B_ 32
#define L_ 8192
#define D_ 256
#define M_ 4097   // L/2 + 1

typedef float f32x4_t __attribute__((ext_vector_type(4)));   // native vec for nontemporal builtin

// ---------------------------------------------------------------------------
// K1: s[b,l] = sigmoid(dot(x[b,l,:], W) + bias).  One wave (64 lanes) per row,
// each lane loads a float4 of x and W (64*4 = 256 = D), shuffle-xor reduce.
// Memory-bound at ~268 MB read; at roofline — unchanged.
// ---------------------------------------------------------------------------
__global__ __launch_bounds__(256) void k_sigmoid_dot(
    const float* __restrict__ x, const float* __restrict__ W,
    const float* __restrict__ bias, float* __restrict__ s)
{
    int row  = (blockIdx.x << 2) + (threadIdx.x >> 6);   // 4 waves/block
    int lane = threadIdx.x & 63;
    const float4 xv = ((const float4*)(x + (size_t)row * D_))[lane];
    const float4 wv = ((const float4*)W)[lane];
    float p = xv.x * wv.x + xv.y * wv.y + xv.z * wv.z + xv.w * wv.w;
#pragma unroll
    for (int off = 32; off > 0; off >>= 1)
        p += __shfl_xor(p, off, 64);
    if (lane == 0) {
        float z = p + bias[0];
        s[row] = 1.0f / (1.0f + expf(-z));
    }
}

// ---------------------------------------------------------------------------
// K2: per batch: strict-local-min mask (zero-padded neighbors, frame 0 forced
// true), wave-shuffle scan for prefix ranks, packed 16 B record per valley:
// (w0 = s0*inv, w1 = s1*inv, p).  One block per batch; each thread owns 32
// contiguous frames bulk-loaded as 8x float4.  ~2 us — unchanged.
// ---------------------------------------------------------------------------
__global__ __launch_bounds__(256) void k_scan(
    const float* __restrict__ s, float4* __restrict__ rec,
    int* __restrict__ counts, float* __restrict__ out_counts)
{
    int b = blockIdx.x;
    const float* sb = s + (size_t)b * L_;
    int t    = threadIdx.x;
    int wid  = t >> 6;
    int lane = t & 63;
    int base = t * 32;

    // vals[j] = s[base - 1 + j], j in [0, 33]; zero-padded at both ends.
    float vals[34];
    vals[0]  = (base == 0) ? 0.0f : sb[base - 1];
    const float4* sb4 = (const float4*)(sb + base);
#pragma unroll
    for (int j = 0; j < 8; j++) {
        float4 q = sb4[j];
        vals[1 + 4 * j] = q.x; vals[2 + 4 * j] = q.y;
        vals[3 + 4 * j] = q.z; vals[4 + 4 * j] = q.w;
    }
    vals[33] = (base + 32 >= L_) ? 0.0f : sb[base + 32];

    unsigned bits = 0;
    int cnt = 0;
#pragma unroll
    for (int i = 0; i < 32; i++) {
        bool m = (base + i == 0)
                 ? true
                 : ((vals[i + 1] < vals[i]) && (vals[i + 1] < vals[i + 2]));
        if (m) { bits |= (1u << i); cnt++; }
    }

    // Wave-level inclusive scan (no barriers), then cross-wave offsets.
    int v = cnt;
#pragma unroll
    for (int off = 1; off < 64; off <<= 1) {
        int u = __shfl_up(v, off, 64);
        if (lane >= off) v += u;
    }
    __shared__ int wsum[4];
    if (lane == 63) wsum[wid] = v;
    __syncthreads();
    int wo = 0;
#pragma unroll
    for (int w = 0; w < 4; w++)
        if (w < wid) wo += wsum[w];
    int excl  = v + wo - cnt;
    int total = wsum[0] + wsum[1] + wsum[2] + wsum[3];

    int k = excl;
#pragma unroll
    for (int i = 0; i < 32; i++) {
        if (bits & (1u << i)) {
            if (k < M_) {                    // defensive: cannot write OOB
                int   p  = base + i;
                float s0 = vals[i + 1];
                float s1 = vals[i + 2];      // == 0 automatically at p == L-1
                float inv = 1.0f / fmaxf(s0 + s1, 1e-6f);
                float4 r;
                r.x = s0 * inv;
                r.y = s1 * inv;
                r.z = __int_as_float(p);
                r.w = 0.0f;
                rec[(size_t)b * M_ + k] = r;
            }
            k++;
        }
    }
    if (t == 0) {
        counts[b]     = total;
        out_counts[b] = (float)total;   // harness reads flat out buffer as f32
    }
}

// ---------------------------------------------------------------------------
// K3: 256-thread blocks, 8 output rows per block (2 per wave, independent).
// Experiment: (a) REVERSED batch traversal — K1 streamed x batch 0..31, so
// batch 31 is hottest in L3; read it first before our own out-writes evict
// it.  (b) nontemporal stores for out (never re-read) so the 134 MB write
// stream doesn't evict x from L2/L3.
// ---------------------------------------------------------------------------
__global__ __launch_bounds__(256) void k_write(
    const float* __restrict__ x, const float4* __restrict__ rec,
    const int* __restrict__ counts, float* __restrict__ out)
{
    int b    = (B_ - 1) - blockIdx.y;    // hottest-in-L3 batches first
    int wid  = threadIdx.x >> 6;
    int lane = threadIdx.x & 63;
    int cnt  = counts[b];
    if (cnt > M_) cnt = M_;              // defensive clamp
    int kb   = blockIdx.x * 8 + wid;
#pragma unroll
    for (int rr = 0; rr < 2; rr++) {
        int k = kb + (rr << 2);
        if (k >= M_) continue;
        f32x4_t* orow = (f32x4_t*)(out + ((size_t)b * M_ + k) * D_);
        if (k >= cnt) {
            f32x4_t z = {0.f, 0.f, 0.f, 0.f};
            __builtin_nontemporal_store(z, &orow[lane]);
            continue;
        }
        float4 r4 = rec[(size_t)b * M_ + k];
        int p = __float_as_int(r4.z);
        if (p < 0) p = 0;
        if (p > L_ - 1) p = L_ - 1;      // defensive clamp
        const float4* xp = (const float4*)(x + ((size_t)b * L_ + p) * D_);
        float4 a = xp[lane];
        const float4* xq = xp + ((p + 1 < L_) ? (D_ / 4) : 0);
        float4 c = xq[lane];
        f32x4_t r;
        r.x = r4.x * a.x + r4.y * c.x;
        r.y = r4.x * a.y + r4.y * c.y;
        r.z = r4.x * a.z + r4.y * c.z;
        r.w = r4.x * a.w + r4.y * c.w;
        __builtin_nontemporal_store(r, &orow[lane]);
    }
}

extern "C" void kernel_launch(void* const* d_in, const int* in_sizes, int n_in,
                              void* d_out, int out_size, void* d_ws, size_t ws_size,
                              hipStream_t stream) {
    const float* x    = (const float*)d_in[0];
    // d_in[1] = olens: unused by the reference
    const float* W    = (const float*)d_in[2];
    const float* bias = (const float*)d_in[3];

    float* out        = (float*)d_out;
    float* out_counts = out + (size_t)B_ * M_ * D_;   // counts tail, as f32

    float*  s      = (float*)d_ws;                                    // B*L f32   (1 MB)
    float4* rec    = (float4*)((char*)d_ws + (size_t)B_ * L_ * 4);    // B*M*16 B  (2 MB)
    int*    counts = (int*)((char*)rec + (size_t)B_ * M_ * 16);       // B i32

    k_sigmoid_dot<<<(B_ * L_) / 4, 256, 0, stream>>>(x, W, bias, s);
    k_scan<<<B_, 256, 0, stream>>>(s, rec, counts, out_counts);
    k_write<<<dim3((M_ + 7) / 8, B_), 256, 0, stream>>>(x, rec, counts, out);
}